// Round 11
// baseline (151.456 us; speedup 1.0000x reference)
//
#include <hip/hip_runtime.h>
#include <math.h>

// PCATemplateMap: x (64,2048,19,19) f32, templates (10,19,19) f32
// outputs: mask (64,1,19,19) then v (64,10), concatenated flat.
//
//  k1: 32-ch tiles staged coalesced into padded LDS rows [32][364] (R9
//      staging). Thread = (c2 0..15, s 0..15): channels {c2, c2+16},
//      24-elem segment -> one template b128 feeds 2 channels (kk=2, halves
//      the R8 template DS wall). QP s-stride 330 (banks rotate), assembly
//      writes per-tile q into per-block Qall[256][10]; the 65-slot S1/S2
//      accumulate runs ONCE per block over Qall (no per-tile fixed cost).
//  k2: one wave per batch. D = S2 - S1 S1^T / C, LAPACK ssyevd port
//      (ssytd2 LDS + ssteqr lane-distributed dd/ee + row-per-lane Z register
//      rotations + argmax + single-column sormtr), fast rcp/rsq arithmetic,
//      branch structure identical to LAPACK (sign-faithful).

#define NB   64
#define NC   2048
#define NHW  361
#define NTMP 10

struct f4 { float x, y, z, w; };
__device__ inline f4 load4u(const float* p){
    f4 r;
    __builtin_memcpy(&r, p, 16);
    return r;
}

__device__ inline float rl(float v, int i){
    return __int_as_float(__builtin_amdgcn_readlane(__float_as_int(v), i));
}

__device__ inline float frcp(float x){
#if __has_builtin(__builtin_amdgcn_rcpf)
    return __builtin_amdgcn_rcpf(x);
#else
    return 1.0f / x;
#endif
}
__device__ inline float frsq(float x){
#if __has_builtin(__builtin_amdgcn_rsqf)
    return __builtin_amdgcn_rsqf(x);
#else
    return 1.0f / sqrtf(x);
#endif
}
__device__ inline float fdivf(float a, float b){ return a * frcp(b); }

// ======================= Kernel 1: partial S1/S2 ==========================
// grid NB*CBLK x 256 threads; 256 ch/block = 8 tiles of 32 (CBLK=8).
template<int CBLK>
__global__ __launch_bounds__(256) void k1_partials(
        const float* __restrict__ x, const float* __restrict__ tmpl,
        float* __restrict__ partial)
{
    constexpr int CPB    = NC / CBLK;        // channels per block (256)
    constexpr int NT     = CPB / 32;         // tiles per block (8)
    constexpr int ROWP   = 364;              // padded row (16B-aligned)
    constexpr int CH_ROW = 91;               // b128 chunks per padded row
    constexpr int CH_TOT = 32 * CH_ROW;      // 2912
    constexpr int KST    = 12;               // staging rounds (last partial)

    __shared__ __align__(16) float xl[32 * ROWP];   // 46.6 KB (QP aliases)
    __shared__ __align__(16) float Tl[NTMP][ROWP];  // 14.6 KB
    __shared__ float Qall[CPB * NTMP];              // 10.2 KB: Qall[c*10+t]
    __shared__ float red[4][66];

    float* qp = xl;   // QP[s*330 + c*10 + t], s<16 -> 5269 floats << 11648

    const int tid  = threadIdx.x;
    const int lane = tid & 63;
    const int wid  = tid >> 6;
    const int b    = blockIdx.x / CBLK;
    const int cb   = blockIdx.x % CBLK;
    const float* xbase = x + ((size_t)b*NC + (size_t)cb*CPB)*NHW;

    for (int idx = tid; idx < NTMP*ROWP; idx += 256){
        int t = idx / ROWP, i = idx - t*ROWP;
        Tl[t][i] = (i < NHW) ? tmpl[t*NHW + i] : 0.f;
    }

    const int c2 = tid & 15;       // channel pair {c2, c2+16}
    const int s  = tid >> 4;       // segment 0..15 (s<15: 24 elems; s15: 360)

    f4 pre[KST];
    auto LOADT = [&](int tile){
        const float* slab = xbase + (size_t)tile*32*NHW;
        #pragma unroll
        for (int k = 0; k < KST; k++){
            const int ch = tid + 256*k;
            if (k < KST-1 || ch < CH_TOT){
                const int c = (int)(((unsigned)ch * 2881u) >> 18);  // ch/91
                const int p = ch - CH_ROW*c;
                pre[k] = load4u(slab + c*NHW + ((p == 90) ? 357 : 4*p));
            }
        }
    };

    LOADT(0);

    for (int tile = 0; tile < NT; tile++){
        // ---- staged regs -> padded LDS rows ----
        #pragma unroll
        for (int k = 0; k < KST; k++){
            const int ch = tid + 256*k;
            if (k < KST-1 || ch < CH_TOT){
                const int c = (int)(((unsigned)ch * 2881u) >> 18);
                const int p = ch - CH_ROW*c;
                if (p == 90){                       // dst 357: 4x b32
                    const int d = c*ROWP + 357;
                    xl[d+0] = pre[k].x; xl[d+1] = pre[k].y;
                    xl[d+2] = pre[k].z; xl[d+3] = pre[k].w;
                } else {
                    *reinterpret_cast<f4*>(&xl[c*ROWP + 4*p]) = pre[k];
                }
            }
        }
        __syncthreads();                             // B1: xl ready
        if (tile + 1 < NT) LOADT(tile + 1);          // prefetch next tile

        // ---- compute: 2 channels x 24-elem segment (kk=2 template reuse) --
        float acc[2][NTMP];
        #pragma unroll
        for (int kk = 0; kk < 2; kk++)
            #pragma unroll
            for (int t = 0; t < NTMP; t++) acc[kk][t] = 0.f;

        if (s < 15){
            #pragma unroll
            for (int j = 0; j < 6; j++){
                const int i0 = 24*s + 4*j;
                const f4 xa = *reinterpret_cast<const f4*>(&xl[c2*ROWP + i0]);
                const f4 xb = *reinterpret_cast<const f4*>(&xl[(c2+16)*ROWP + i0]);
                #pragma unroll
                for (int t = 0; t < NTMP; t++){
                    const f4 tv = *reinterpret_cast<const f4*>(&Tl[t][i0]);
                    acc[0][t] += xa.x*tv.x + xa.y*tv.y + xa.z*tv.z + xa.w*tv.w;
                    acc[1][t] += xb.x*tv.x + xb.y*tv.y + xb.z*tv.z + xb.w*tv.w;
                }
            }
        } else {                                     // s == 15: elem 360
            const float xa = xl[c2*ROWP + 360];
            const float xb = xl[(c2+16)*ROWP + 360];
            #pragma unroll
            for (int t = 0; t < NTMP; t++){
                acc[0][t] += xa * Tl[t][360];
                acc[1][t] += xb * Tl[t][360];
            }
        }
        __syncthreads();                             // B2: xl reads done

        // ---- QP scatter (aliases xl; s-stride 330 -> banks rotate) ----
        #pragma unroll
        for (int t = 0; t < NTMP; t++){
            qp[s*330 + c2*NTMP + t]        = acc[0][t];
            qp[s*330 + (c2+16)*NTMP + t]   = acc[1][t];
        }
        __syncthreads();                             // B3: QP ready

        // ---- assembly: Qall[tile*320 + idx] = sum_s QP[s][idx] ----
        for (int idx = tid; idx < 32*NTMP; idx += 256){
            float v = 0.f;
            #pragma unroll
            for (int ss = 0; ss < 16; ss++) v += qp[ss*330 + idx];
            Qall[tile*(32*NTMP) + idx] = v;
        }
        __syncthreads();                             // B4: QP consumed
    }

    // ---- slot accumulate ONCE over all 256 channels (wave-parallel) ----
    int tA, uA;
    const bool isS2 = (lane < 55);
    if (isS2){
        int k = lane, t = 0;
        while (k >= NTMP - t){ k -= NTMP - t; t++; }
        tA = t; uA = t + k;
    } else { tA = lane - 55; uA = tA; }
    float sv = 0.f, s1v = 0.f;

    for (int c = wid*64; c < wid*64 + 64; c++){
        const float qt = Qall[c*NTMP + tA];
        const float qu = Qall[c*NTMP + uA];
        if (isS2) sv += qt*qu; else s1v += qt;
        if (lane == 54) s1v += qu;                   // S1[9]
    }

    if (isS2) red[wid][10 + lane] = sv;
    else      red[wid][lane - 55] = s1v;
    if (lane == 54) red[wid][9] = s1v;
    __syncthreads();
    if (tid < 65){
        partial[(size_t)blockIdx.x*65 + tid] =
            red[0][tid] + red[1][tid] + red[2][tid] + red[3][tid];
    }
}

// =================== LAPACK helpers (fast arithmetic) =====================
__device__ inline float f_sign(float a, float b){
    return (b >= 0.f) ? fabsf(a) : -fabsf(a);     // Fortran SIGN(a,b)
}

__device__ inline float slapy2(float xx, float yy){
#pragma clang fp contract(off)
    float xa = fabsf(xx), ya = fabsf(yy);
    float w = fmaxf(xa, ya), z = fminf(xa, ya);
    if (z == 0.f) return w;
    float q = fdivf(z, w);
    return w * sqrtf(1.f + q*q);
}

// LAPACK >= 3.10 slartg convention (c >= 0); same branches, rsq arithmetic.
__device__ inline void slartg(float f, float g, float* cs, float* sn, float* rr){
#pragma clang fp contract(off)
    const float safmin = 0x1.0p-126f;
    const float safmax = 0x1.0p+126f;
    const float rtmin  = 0x1.0p-63f;
    const float rtmax  = 6.5211589e18f;  // sqrt(safmax/2)
    float f1 = fabsf(f), g1 = fabsf(g);
    if (g == 0.f){ *cs = 1.f; *sn = 0.f; *rr = f; }
    else if (f == 0.f){
        *cs = 0.f;
        *sn = (g >= 0.f) ? 1.f : -1.f;
        *rr = g1;
    } else {
        if (f1 > rtmin && f1 < rtmax && g1 > rtmin && g1 < rtmax){
            float rr2 = f*f + g*g;
            float inv = frsq(rr2);
            float d   = rr2 * inv;            // sqrt(f^2+g^2)
            float sgn = (f >= 0.f) ? 1.f : -1.f;
            *cs = f1 * inv;
            *rr = sgn * d;
            *sn = g * inv * sgn;
        } else {
            float u = fminf(safmax, fmaxf(safmin, fmaxf(f1, g1)));
            float fs = fdivf(f, u), gs = fdivf(g, u);
            float rr2 = fs*fs + gs*gs;
            float inv = frsq(rr2);
            float d   = rr2 * inv;
            *cs = fabsf(fs) * inv;
            float r0 = (f >= 0.f) ? d : -d;
            *sn = fdivf(gs, r0);
            *rr = r0 * u;
        }
    }
}

__device__ inline void slaev2(float a, float b, float c,
                              float* rt1, float* rt2, float* cs1, float* sn1){
#pragma clang fp contract(off)
    float sm = a + c;
    float df = a - c;
    float adf = fabsf(df);
    float tb = b + b;
    float ab = fabsf(tb);
    float acmx, acmn;
    if (fabsf(a) > fabsf(c)){ acmx = a; acmn = c; } else { acmx = c; acmn = a; }
    float rt;
    if (adf > ab){ float q = fdivf(ab, adf); rt = adf*sqrtf(1.f + q*q); }
    else if (adf < ab){ float q = fdivf(adf, ab); rt = ab*sqrtf(1.f + q*q); }
    else { rt = ab*sqrtf(2.f); }
    int sgn1;
    if (sm < 0.f){
        *rt1 = 0.5f*(sm - rt); sgn1 = -1;
        float inv1 = frcp(*rt1);
        *rt2 = (acmx*inv1)*acmn - (b*inv1)*b;
    } else if (sm > 0.f){
        *rt1 = 0.5f*(sm + rt); sgn1 = 1;
        float inv1 = frcp(*rt1);
        *rt2 = (acmx*inv1)*acmn - (b*inv1)*b;
    } else {
        *rt1 = 0.5f*rt; *rt2 = -0.5f*rt; sgn1 = 1;
    }
    float cs; int sgn2;
    if (df >= 0.f){ cs = df + rt; sgn2 = 1; }
    else { cs = df - rt; sgn2 = -1; }
    float acs = fabsf(cs);
    if (acs > ab){
        float ct = fdivf(-tb, cs);
        *sn1 = frsq(1.f + ct*ct);
        *cs1 = ct * (*sn1);
    } else {
        if (ab == 0.f){ *cs1 = 1.f; *sn1 = 0.f; }
        else {
            float tn = fdivf(-cs, tb);
            *cs1 = frsq(1.f + tn*tn);
            *sn1 = tn * (*cs1);
        }
    }
    if (sgn1 == sgn2){
        float tn = *cs1;
        *cs1 = -(*sn1);
        *sn1 = tn;
    }
}

#define A_(i,j) Aa[((j)-1)*10 + ((i)-1)]

// wave-cooperative ssyevd('V','L') n=10; lanes 0..63 of one wave.
__device__ void eig10_wave(int lane, float* Aa, float* dd, float* ee,
                           float* tt, float* px, float* vout)
{
#pragma clang fp contract(off)
    const int n = 10;

    // ---------------- ssytd2 (lower) ----------------
    for (int i = 1; i <= n-1; i++){
        float alpha = A_(i+1, i);
        float ssq = 0.f;
        for (int k = i+2; k <= n; k++){ float v = A_(k,i); ssq += v*v; }
        float xnorm = sqrtf(ssq);
        float taui;
        if (xnorm == 0.f){
            taui = 0.f;
        } else {
            float beta = -f_sign(slapy2(alpha, xnorm), alpha);
            taui = fdivf(beta - alpha, beta);
            float sc = frcp(alpha - beta);
            for (int k = i+2; k <= n; k++) A_(k,i) *= sc;   // all lanes same value
            alpha = beta;
        }
        ee[i] = alpha;
        if (taui != 0.f){
            A_(i+1, i) = 1.f;
            const int n2 = n - i;
            if (lane >= 1 && lane <= n2){
                const int l2 = lane;
                float p = 0.f;
                for (int j = 1; j <= l2-1; j++)
                    p = p + (taui * A_(i+j, i)) * A_(i+l2, i+j);
                p = p + (taui * A_(i+l2, i)) * A_(i+l2, i+l2);
                float temp2 = 0.f;
                for (int ii2 = l2+1; ii2 <= n2; ii2++)
                    temp2 = temp2 + A_(i+ii2, i+l2) * A_(i+ii2, i);
                p = p + taui * temp2;
                px[l2] = p;
            }
            float dot = 0.f;
            for (int j = 1; j <= n2; j++) dot = dot + px[j] * A_(i+j, i);
            float alpha2 = -0.5f * taui * dot;
            if (lane >= 1 && lane <= n2)
                px[lane] = px[lane] + alpha2 * A_(i+lane, i);
            if (lane >= 1 && lane <= n2){
                const int j = lane;
                float xj = A_(i+j, i);
                float yj = px[j];
                if (xj != 0.f || yj != 0.f){
                    float temp1 = -yj;
                    float temp2 = -xj;
                    for (int ii2 = j; ii2 <= n2; ii2++){
                        A_(i+ii2, i+j) = A_(i+ii2, i+j)
                                       + A_(i+ii2, i)*temp1 + px[ii2]*temp2;
                    }
                }
            }
            A_(i+1, i) = ee[i];
        }
        dd[i] = A_(i, i);
        tt[i] = taui;
    }
    dd[n] = A_(n, n);

    // ---------------- lane-distributed state ----------------
    float dd_r = (lane >= 1 && lane <= n)   ? dd[lane] : 0.f;
    float ee_r = (lane >= 1 && lane <= n-1) ? ee[lane] : 0.f;
    float wkc_r = 0.f, wks_r = 0.f;
    float z[10];                 // row-per-lane: z[c] = Z(lane+1, c+1), lane 0..9
    #pragma unroll
    for (int c = 0; c < 10; c++) z[c] = (lane == c) ? 1.f : 0.f;

#define ZCASE(J)  { float a = z[(J)]; float bz = z[(J)-1];                 \
                    z[(J)] = c_*a - s_*bz;  z[(J)-1] = s_*a + c_*bz; }
    auto ZROT = [&](int jj, float c_, float s_){
        switch (jj){
            case 1: ZCASE(1) break;
            case 2: ZCASE(2) break;
            case 3: ZCASE(3) break;
            case 4: ZCASE(4) break;
            case 5: ZCASE(5) break;
            case 6: ZCASE(6) break;
            case 7: ZCASE(7) break;
            case 8: ZCASE(8) break;
            default: ZCASE(9) break;
        }
    };
#undef ZCASE

    // ---------------- ssteqr 'I' ----------------
    const float eps    = 0x1.0p-24f;
    const float eps2   = 0x1.0p-48f;
    const float safmin = 0x1.0p-126f;
    const int nmaxit = n * 30;
    int jtot = 0;
    int l1 = 1;

    while (true){
        if (l1 > n) break;
        if (l1 > 1){ if (lane == l1-1) ee_r = 0.f; }
        int m = n;
        if (l1 <= n-1){
            for (m = l1; m <= n-1; m++){
                float tst = fabsf(rl(ee_r, m));
                if (tst == 0.f) break;
                if (tst <= (sqrtf(fabsf(rl(dd_r, m))) * sqrtf(fabsf(rl(dd_r, m+1)))) * eps){
                    if (lane == m) ee_r = 0.f;
                    break;
                }
            }
        }
        int l = l1;
        int lsv = l;
        int lend = m;
        int lendsv = lend;
        l1 = m + 1;
        if (lend == l) continue;

        float anorm = 0.f;
        for (int k = l; k <= lend; k++)   anorm = fmaxf(anorm, fabsf(rl(dd_r, k)));
        for (int k = l; k <= lend-1; k++) anorm = fmaxf(anorm, fabsf(rl(ee_r, k)));
        if (anorm == 0.f) continue;

        if (fabsf(rl(dd_r, lend)) < fabsf(rl(dd_r, l))){
            lend = lsv;
            l = lendsv;
        }

        if (lend > l){
            // -------- QL --------
            while (true){
                int mq = lend;
                if (l != lend){
                    for (int t2 = l; t2 <= lend-1; t2++){
                        float ev = fabsf(rl(ee_r, t2));
                        if (ev*ev <= (eps2*fabsf(rl(dd_r, t2)))*fabsf(rl(dd_r, t2+1)) + safmin){
                            mq = t2; break;
                        }
                    }
                }
                if (mq < lend){ if (lane == mq) ee_r = 0.f; }
                float p = rl(dd_r, l);
                if (mq == l){
                    l = l + 1;
                    if (l <= lend) continue;
                    break;
                }
                if (mq == l+1){
                    float rt1, rt2, cc, ss;
                    slaev2(rl(dd_r, l), rl(ee_r, l), rl(dd_r, l+1), &rt1, &rt2, &cc, &ss);
                    ZROT(l, cc, ss);
                    if (lane == l)   dd_r = rt1;
                    if (lane == l+1) dd_r = rt2;
                    if (lane == l)   ee_r = 0.f;
                    l += 2;
                    if (l <= lend) continue;
                    break;
                }
                if (jtot == nmaxit) break;
                jtot++;
                float g = fdivf(rl(dd_r, l+1) - p, 2.f * rl(ee_r, l));
                float r0 = slapy2(g, 1.f);
                g = rl(dd_r, mq) - p + fdivf(rl(ee_r, l), g + f_sign(r0, g));
                float ss = 1.f, cc = 1.f;
                p = 0.f;
                for (int i2 = mq-1; i2 >= l; i2--){
                    float e2 = rl(ee_r, i2);
                    float ff = ss * e2;
                    float bb = cc * e2;
                    float rr;
                    slartg(g, ff, &cc, &ss, &rr);
                    if (i2 != mq-1){ if (lane == i2+1) ee_r = rr; }
                    g = rl(dd_r, i2+1) - p;
                    rr = (rl(dd_r, i2) - g)*ss + 2.f*cc*bb;
                    p = ss*rr;
                    if (lane == i2+1) dd_r = g + p;
                    g = cc*rr - bb;
                    if (lane == i2){ wkc_r = cc; wks_r = -ss; }
                }
                for (int jj = mq-1; jj >= l; jj--){
                    float ct = rl(wkc_r, jj), st = rl(wks_r, jj);
                    if (ct != 1.f || st != 0.f) ZROT(jj, ct, st);
                }
                if (lane == l) dd_r = dd_r - p;
                if (lane == l) ee_r = g;
            }
        } else {
            // -------- QR --------
            while (true){
                int mq = lend;
                if (l != lend){
                    for (int t2 = l; t2 >= lend+1; t2--){
                        float ev = fabsf(rl(ee_r, t2-1));
                        if (ev*ev <= (eps2*fabsf(rl(dd_r, t2)))*fabsf(rl(dd_r, t2-1)) + safmin){
                            mq = t2; break;
                        }
                    }
                }
                if (mq > lend){ if (lane == mq-1) ee_r = 0.f; }
                float p = rl(dd_r, l);
                if (mq == l){
                    l = l - 1;
                    if (l >= lend) continue;
                    break;
                }
                if (mq == l-1){
                    float rt1, rt2, cc, ss;
                    slaev2(rl(dd_r, l-1), rl(ee_r, l-1), rl(dd_r, l), &rt1, &rt2, &cc, &ss);
                    ZROT(l-1, cc, ss);
                    if (lane == l-1) dd_r = rt1;
                    if (lane == l)   dd_r = rt2;
                    if (lane == l-1) ee_r = 0.f;
                    l -= 2;
                    if (l >= lend) continue;
                    break;
                }
                if (jtot == nmaxit) break;
                jtot++;
                float g = fdivf(rl(dd_r, l-1) - p, 2.f * rl(ee_r, l-1));
                float r0 = slapy2(g, 1.f);
                g = rl(dd_r, mq) - p + fdivf(rl(ee_r, l-1), g + f_sign(r0, g));
                float ss = 1.f, cc = 1.f;
                p = 0.f;
                for (int i2 = mq; i2 <= l-1; i2++){
                    float e2 = rl(ee_r, i2);
                    float ff = ss * e2;
                    float bb = cc * e2;
                    float rr;
                    slartg(g, ff, &cc, &ss, &rr);
                    if (i2 != mq){ if (lane == i2-1) ee_r = rr; }
                    g = rl(dd_r, i2) - p;
                    rr = (rl(dd_r, i2+1) - g)*ss + 2.f*cc*bb;
                    p = ss*rr;
                    if (lane == i2) dd_r = g + p;
                    g = cc*rr - bb;
                    if (lane == i2){ wkc_r = cc; wks_r = ss; }
                }
                for (int jj = mq; jj <= l-1; jj++){
                    float ct = rl(wkc_r, jj), st = rl(wks_r, jj);
                    if (ct != 1.f || st != 0.f) ZROT(jj, ct, st);
                }
                if (lane == l)   dd_r = dd_r - p;
                if (lane == l-1) ee_r = g;
            }
        }
        if (jtot < nmaxit) continue;
        break;
    }

    // ---------------- argmax (ascending sort's last == max) ----------------
    int kmax = 1;
    float pmax = rl(dd_r, 1);
    for (int j = 2; j <= n; j++){
        float dj = rl(dd_r, j);
        if (dj > pmax){ pmax = dj; kmax = j; }
    }

    // extract column kmax (row-per-lane): lane L holds row L+1
    float vc;
    switch (kmax){
        case 1:  vc = z[0]; break;
        case 2:  vc = z[1]; break;
        case 3:  vc = z[2]; break;
        case 4:  vc = z[3]; break;
        case 5:  vc = z[4]; break;
        case 6:  vc = z[5]; break;
        case 7:  vc = z[6]; break;
        case 8:  vc = z[7]; break;
        case 9:  vc = z[8]; break;
        default: vc = z[9]; break;
    }

    // ---------------- sormtr 'L','L','N' on the single column ------------
    // row r lives on lane r-1.
    for (int i = n-1; i >= 1; i--){
        float taui = tt[i];
        if (taui != 0.f){
            float s1 = rl(vc, i);                       // row i+1
            for (int r2 = i+2; r2 <= n; r2++) s1 = s1 + A_(r2, i) * rl(vc, r2-1);
            s1 = taui * s1;
            if (lane == i) vc = vc - s1;                // row i+1
            if (lane >= i+1 && lane <= n-1)             // rows i+2..n
                vc = vc - A_(lane+1, i) * s1;
        }
    }
    if (lane < n) vout[lane] = vc;
}

// ======================= Kernel 2: D, eigh, outputs =======================
__global__ __launch_bounds__(64) void k2_eig(
        const float* __restrict__ partial, const float* __restrict__ tmpl,
        float* __restrict__ out, int cblk)
{
    __shared__ float SS[66];
    __shared__ float Aa[100];
    __shared__ float dd[12], ee[12], tt[12], px[12], vout[12];
    const int lane = threadIdx.x;
    const int b = blockIdx.x;

    for (int i = lane; i < 65; i += 64){
        float s = 0.f;
        for (int p = 0; p < cblk; p++)
            s += partial[((size_t)b*cblk + p)*65 + i];
        SS[i] = s;
    }
    __syncthreads();

    // D[t][s] = S2 - S1 S1^T / C (exactly symmetric), col-major in Aa
    for (int idx = lane; idx < 100; idx += 64){
        int t = idx % 10, s2 = idx / 10;
        int lo = t < s2 ? t : s2, hi = t < s2 ? s2 : t;
        int pk = 10*lo - (lo*(lo-1))/2 + (hi - lo);
        Aa[s2*10 + t] = SS[10 + pk] - SS[t]*SS[s2]*(1.0f/2048.0f);
    }
    __syncthreads();

    eig10_wave(lane, Aa, dd, ee, tt, px, vout);
    __syncthreads();

    if (lane < NTMP)
        out[(size_t)NB*NHW + (size_t)b*NTMP + lane] = vout[lane];

    for (int i = lane; i < NHW; i += 64){
        float m2 = 0.f;
        #pragma unroll
        for (int t = 0; t < NTMP; t++) m2 += vout[t] * tmpl[t*NHW + i];
        out[(size_t)b*NHW + i] = m2;
    }
}

// ============================== launcher ==================================
extern "C" void kernel_launch(void* const* d_in, const int* in_sizes, int n_in,
                              void* d_out, int out_size, void* d_ws, size_t ws_size,
                              hipStream_t stream)
{
    const float* x    = (const float*)d_in[0];
    const float* tmpl = (const float*)d_in[1];
    float* out = (float*)d_out;
    float* partial = (float*)d_ws;

    if (ws_size >= (size_t)NB*8*65*sizeof(float)){
        // 512 blocks (2/CU), 256 ch/block = 8 tiles of 32
        k1_partials<8><<<dim3(NB*8), dim3(256), 0, stream>>>(x, tmpl, partial);
        k2_eig<<<dim3(NB), dim3(64), 0, stream>>>(partial, tmpl, out, 8);
    } else if (ws_size >= (size_t)NB*4*65*sizeof(float)){
        k1_partials<4><<<dim3(NB*4), dim3(256), 0, stream>>>(x, tmpl, partial);
        k2_eig<<<dim3(NB), dim3(64), 0, stream>>>(partial, tmpl, out, 4);
    } else {
        k1_partials<2><<<dim3(NB*2), dim3(256), 0, stream>>>(x, tmpl, partial);
        k2_eig<<<dim3(NB), dim3(64), 0, stream>>>(partial, tmpl, out, 2);
    }
}

// Round 12
// 134.823 us; speedup vs baseline: 1.1234x; 1.1234x over previous
//
#include <hip/hip_runtime.h>
#include <math.h>

// PCATemplateMap: x (64,2048,19,19) f32, templates (10,19,19) f32
// outputs: mask (64,1,19,19) then v (64,10), concatenated flat.
//
//  k1 (H1 test: 4 waves/SIMD): 512-thread blocks, 2 blocks/CU = 16 waves/CU
//     (all prior rounds ran 8). 32-ch tiles staged coalesced into padded
//     LDS rows [32][364]; thread = (c2 0..15, s 0..31): channels {c2,c2+16},
//     12-elem segment, kk=2 template reuse (4 distinct T addrs/wave ->
//     broadcast). QP s-stride 330 -> Qall -> one slot pass per block.
//  k2: one wave per batch. D = S2 - S1 S1^T / C, LAPACK ssyevd port
//     (ssytd2 LDS + ssteqr lane-distributed dd/ee + row-per-lane Z register
//     rotations + argmax + single-column sormtr), fast rcp/rsq arithmetic,
//     branch structure identical to LAPACK (sign-faithful).

#define NB   64
#define NC   2048
#define NHW  361
#define NTMP 10

struct f4 { float x, y, z, w; };
__device__ inline f4 load4u(const float* p){
    f4 r;
    __builtin_memcpy(&r, p, 16);
    return r;
}

__device__ inline float rl(float v, int i){
    return __int_as_float(__builtin_amdgcn_readlane(__float_as_int(v), i));
}

__device__ inline float frcp(float x){
#if __has_builtin(__builtin_amdgcn_rcpf)
    return __builtin_amdgcn_rcpf(x);
#else
    return 1.0f / x;
#endif
}
__device__ inline float frsq(float x){
#if __has_builtin(__builtin_amdgcn_rsqf)
    return __builtin_amdgcn_rsqf(x);
#else
    return 1.0f / sqrtf(x);
#endif
}
__device__ inline float fdivf(float a, float b){ return a * frcp(b); }

// ======================= Kernel 1: partial S1/S2 ==========================
// grid NB*CBLK x 512 threads (8 waves); 256 ch/block = 8 tiles of 32 (CBLK=8).
template<int CBLK>
__global__ __launch_bounds__(512) void k1_partials(
        const float* __restrict__ x, const float* __restrict__ tmpl,
        float* __restrict__ partial)
{
    constexpr int CPB    = NC / CBLK;        // channels per block (256)
    constexpr int NT     = CPB / 32;         // tiles per block (8)
    constexpr int ROWP   = 364;              // padded row (16B-aligned)
    constexpr int CH_ROW = 91;               // b128 chunks per padded row
    constexpr int CH_TOT = 32 * CH_ROW;      // 2912
    constexpr int KST    = (CH_TOT + 511) / 512;   // 6 staging rounds

    __shared__ __align__(16) float xl[32 * ROWP];   // 46.6 KB (QP aliases)
    __shared__ __align__(16) float Tl[NTMP][ROWP];  // 14.6 KB
    __shared__ float Qall[CPB * NTMP];              // 10.2 KB
    __shared__ float red[8][66];                    // 2.1 KB

    float* qp = xl;   // QP[s*330 + c*10 + t]: 30*330+320 = 10220 <= 11648

    const int tid  = threadIdx.x;
    const int lane = tid & 63;
    const int wid  = tid >> 6;               // 0..7
    const int b    = blockIdx.x / CBLK;
    const int cb   = blockIdx.x % CBLK;
    const float* xbase = x + ((size_t)b*NC + (size_t)cb*CPB)*NHW;

    for (int idx = tid; idx < NTMP*ROWP; idx += 512){
        int t = idx / ROWP, i = idx - t*ROWP;
        Tl[t][i] = (i < NHW) ? tmpl[t*NHW + i] : 0.f;
    }

    const int c2 = tid & 15;       // channel pair {c2, c2+16}
    const int s  = tid >> 4;       // segment 0..31 (s<30: 12 elems; s30: 360)

    f4 pre[KST];
    auto LOADT = [&](int tile){
        const float* slab = xbase + (size_t)tile*32*NHW;
        #pragma unroll
        for (int k = 0; k < KST; k++){
            const int ch = tid + 512*k;
            if (k < KST-1 || ch < CH_TOT){
                const int c = (int)(((unsigned)ch * 2881u) >> 18);  // ch/91
                const int p = ch - CH_ROW*c;
                pre[k] = load4u(slab + c*NHW + ((p == 90) ? 357 : 4*p));
            }
        }
    };

    LOADT(0);

    for (int tile = 0; tile < NT; tile++){
        // ---- staged regs -> padded LDS rows ----
        #pragma unroll
        for (int k = 0; k < KST; k++){
            const int ch = tid + 512*k;
            if (k < KST-1 || ch < CH_TOT){
                const int c = (int)(((unsigned)ch * 2881u) >> 18);
                const int p = ch - CH_ROW*c;
                if (p == 90){                       // dst 357: 4x b32
                    const int d = c*ROWP + 357;
                    xl[d+0] = pre[k].x; xl[d+1] = pre[k].y;
                    xl[d+2] = pre[k].z; xl[d+3] = pre[k].w;
                } else {
                    *reinterpret_cast<f4*>(&xl[c*ROWP + 4*p]) = pre[k];
                }
            }
        }
        __syncthreads();                             // B1: xl ready
        if (tile + 1 < NT) LOADT(tile + 1);          // prefetch next tile

        // ---- compute: 2 channels x 12-elem segment (kk=2) ----
        float acc[2][NTMP];
        #pragma unroll
        for (int kk = 0; kk < 2; kk++)
            #pragma unroll
            for (int t = 0; t < NTMP; t++) acc[kk][t] = 0.f;

        if (s < 30){
            #pragma unroll
            for (int j = 0; j < 3; j++){
                const int i0 = 12*s + 4*j;
                const f4 xa = *reinterpret_cast<const f4*>(&xl[c2*ROWP + i0]);
                const f4 xb = *reinterpret_cast<const f4*>(&xl[(c2+16)*ROWP + i0]);
                #pragma unroll
                for (int t = 0; t < NTMP; t++){
                    const f4 tv = *reinterpret_cast<const f4*>(&Tl[t][i0]);
                    acc[0][t] += xa.x*tv.x + xa.y*tv.y + xa.z*tv.z + xa.w*tv.w;
                    acc[1][t] += xb.x*tv.x + xb.y*tv.y + xb.z*tv.z + xb.w*tv.w;
                }
            }
        } else if (s == 30){                         // elem 360
            const float xa = xl[c2*ROWP + 360];
            const float xb = xl[(c2+16)*ROWP + 360];
            #pragma unroll
            for (int t = 0; t < NTMP; t++){
                acc[0][t] += xa * Tl[t][360];
                acc[1][t] += xb * Tl[t][360];
            }
        }                                            // s == 31: idle
        __syncthreads();                             // B2: xl reads done

        // ---- QP scatter (aliases xl) ----
        if (s <= 30){
            #pragma unroll
            for (int t = 0; t < NTMP; t++){
                qp[s*330 + c2*NTMP + t]      = acc[0][t];
                qp[s*330 + (c2+16)*NTMP + t] = acc[1][t];
            }
        }
        __syncthreads();                             // B3: QP ready

        // ---- assembly: Qall[tile*320 + idx] = sum_{s=0..30} QP ----
        if (tid < 320){
            float v = 0.f;
            #pragma unroll
            for (int ss = 0; ss < 31; ss++) v += qp[ss*330 + tid];
            Qall[tile*(32*NTMP) + tid] = v;
        }
        __syncthreads();                             // B4: QP consumed
    }

    // ---- slot accumulate ONCE over 256 channels (8 waves x 32 ch) ----
    int tA, uA;
    const bool isS2 = (lane < 55);
    if (isS2){
        int k = lane, t = 0;
        while (k >= NTMP - t){ k -= NTMP - t; t++; }
        tA = t; uA = t + k;
    } else { tA = lane - 55; uA = tA; }
    float sv = 0.f, s1v = 0.f;

    for (int c = wid*32; c < wid*32 + 32; c++){
        const float qt = Qall[c*NTMP + tA];
        const float qu = Qall[c*NTMP + uA];
        if (isS2) sv += qt*qu; else s1v += qt;
        if (lane == 54) s1v += qu;                   // S1[9]
    }

    if (isS2) red[wid][10 + lane] = sv;
    else      red[wid][lane - 55] = s1v;
    if (lane == 54) red[wid][9] = s1v;
    __syncthreads();
    if (tid < 65){
        float v = 0.f;
        #pragma unroll
        for (int w = 0; w < 8; w++) v += red[w][tid];
        partial[(size_t)blockIdx.x*65 + tid] = v;
    }
}

// =================== LAPACK helpers (fast arithmetic) =====================
__device__ inline float f_sign(float a, float b){
    return (b >= 0.f) ? fabsf(a) : -fabsf(a);     // Fortran SIGN(a,b)
}

__device__ inline float slapy2(float xx, float yy){
#pragma clang fp contract(off)
    float xa = fabsf(xx), ya = fabsf(yy);
    float w = fmaxf(xa, ya), z = fminf(xa, ya);
    if (z == 0.f) return w;
    float q = fdivf(z, w);
    return w * sqrtf(1.f + q*q);
}

// LAPACK >= 3.10 slartg convention (c >= 0); same branches, rsq arithmetic.
__device__ inline void slartg(float f, float g, float* cs, float* sn, float* rr){
#pragma clang fp contract(off)
    const float safmin = 0x1.0p-126f;
    const float safmax = 0x1.0p+126f;
    const float rtmin  = 0x1.0p-63f;
    const float rtmax  = 6.5211589e18f;  // sqrt(safmax/2)
    float f1 = fabsf(f), g1 = fabsf(g);
    if (g == 0.f){ *cs = 1.f; *sn = 0.f; *rr = f; }
    else if (f == 0.f){
        *cs = 0.f;
        *sn = (g >= 0.f) ? 1.f : -1.f;
        *rr = g1;
    } else {
        if (f1 > rtmin && f1 < rtmax && g1 > rtmin && g1 < rtmax){
            float rr2 = f*f + g*g;
            float inv = frsq(rr2);
            float d   = rr2 * inv;            // sqrt(f^2+g^2)
            float sgn = (f >= 0.f) ? 1.f : -1.f;
            *cs = f1 * inv;
            *rr = sgn * d;
            *sn = g * inv * sgn;
        } else {
            float u = fminf(safmax, fmaxf(safmin, fmaxf(f1, g1)));
            float fs = fdivf(f, u), gs = fdivf(g, u);
            float rr2 = fs*fs + gs*gs;
            float inv = frsq(rr2);
            float d   = rr2 * inv;
            *cs = fabsf(fs) * inv;
            float r0 = (f >= 0.f) ? d : -d;
            *sn = fdivf(gs, r0);
            *rr = r0 * u;
        }
    }
}

__device__ inline void slaev2(float a, float b, float c,
                              float* rt1, float* rt2, float* cs1, float* sn1){
#pragma clang fp contract(off)
    float sm = a + c;
    float df = a - c;
    float adf = fabsf(df);
    float tb = b + b;
    float ab = fabsf(tb);
    float acmx, acmn;
    if (fabsf(a) > fabsf(c)){ acmx = a; acmn = c; } else { acmx = c; acmn = a; }
    float rt;
    if (adf > ab){ float q = fdivf(ab, adf); rt = adf*sqrtf(1.f + q*q); }
    else if (adf < ab){ float q = fdivf(adf, ab); rt = ab*sqrtf(1.f + q*q); }
    else { rt = ab*sqrtf(2.f); }
    int sgn1;
    if (sm < 0.f){
        *rt1 = 0.5f*(sm - rt); sgn1 = -1;
        float inv1 = frcp(*rt1);
        *rt2 = (acmx*inv1)*acmn - (b*inv1)*b;
    } else if (sm > 0.f){
        *rt1 = 0.5f*(sm + rt); sgn1 = 1;
        float inv1 = frcp(*rt1);
        *rt2 = (acmx*inv1)*acmn - (b*inv1)*b;
    } else {
        *rt1 = 0.5f*rt; *rt2 = -0.5f*rt; sgn1 = 1;
    }
    float cs; int sgn2;
    if (df >= 0.f){ cs = df + rt; sgn2 = 1; }
    else { cs = df - rt; sgn2 = -1; }
    float acs = fabsf(cs);
    if (acs > ab){
        float ct = fdivf(-tb, cs);
        *sn1 = frsq(1.f + ct*ct);
        *cs1 = ct * (*sn1);
    } else {
        if (ab == 0.f){ *cs1 = 1.f; *sn1 = 0.f; }
        else {
            float tn = fdivf(-cs, tb);
            *cs1 = frsq(1.f + tn*tn);
            *sn1 = tn * (*cs1);
        }
    }
    if (sgn1 == sgn2){
        float tn = *cs1;
        *cs1 = -(*sn1);
        *sn1 = tn;
    }
}

#define A_(i,j) Aa[((j)-1)*10 + ((i)-1)]

// wave-cooperative ssyevd('V','L') n=10; lanes 0..63 of one wave.
__device__ void eig10_wave(int lane, float* Aa, float* dd, float* ee,
                           float* tt, float* px, float* vout)
{
#pragma clang fp contract(off)
    const int n = 10;

    // ---------------- ssytd2 (lower) ----------------
    for (int i = 1; i <= n-1; i++){
        float alpha = A_(i+1, i);
        float ssq = 0.f;
        for (int k = i+2; k <= n; k++){ float v = A_(k,i); ssq += v*v; }
        float xnorm = sqrtf(ssq);
        float taui;
        if (xnorm == 0.f){
            taui = 0.f;
        } else {
            float beta = -f_sign(slapy2(alpha, xnorm), alpha);
            taui = fdivf(beta - alpha, beta);
            float sc = frcp(alpha - beta);
            for (int k = i+2; k <= n; k++) A_(k,i) *= sc;   // all lanes same value
            alpha = beta;
        }
        ee[i] = alpha;
        if (taui != 0.f){
            A_(i+1, i) = 1.f;
            const int n2 = n - i;
            if (lane >= 1 && lane <= n2){
                const int l2 = lane;
                float p = 0.f;
                for (int j = 1; j <= l2-1; j++)
                    p = p + (taui * A_(i+j, i)) * A_(i+l2, i+j);
                p = p + (taui * A_(i+l2, i)) * A_(i+l2, i+l2);
                float temp2 = 0.f;
                for (int ii2 = l2+1; ii2 <= n2; ii2++)
                    temp2 = temp2 + A_(i+ii2, i+l2) * A_(i+ii2, i);
                p = p + taui * temp2;
                px[l2] = p;
            }
            float dot = 0.f;
            for (int j = 1; j <= n2; j++) dot = dot + px[j] * A_(i+j, i);
            float alpha2 = -0.5f * taui * dot;
            if (lane >= 1 && lane <= n2)
                px[lane] = px[lane] + alpha2 * A_(i+lane, i);
            if (lane >= 1 && lane <= n2){
                const int j = lane;
                float xj = A_(i+j, i);
                float yj = px[j];
                if (xj != 0.f || yj != 0.f){
                    float temp1 = -yj;
                    float temp2 = -xj;
                    for (int ii2 = j; ii2 <= n2; ii2++){
                        A_(i+ii2, i+j) = A_(i+ii2, i+j)
                                       + A_(i+ii2, i)*temp1 + px[ii2]*temp2;
                    }
                }
            }
            A_(i+1, i) = ee[i];
        }
        dd[i] = A_(i, i);
        tt[i] = taui;
    }
    dd[n] = A_(n, n);

    // ---------------- lane-distributed state ----------------
    float dd_r = (lane >= 1 && lane <= n)   ? dd[lane] : 0.f;
    float ee_r = (lane >= 1 && lane <= n-1) ? ee[lane] : 0.f;
    float wkc_r = 0.f, wks_r = 0.f;
    float z[10];                 // row-per-lane: z[c] = Z(lane+1, c+1), lane 0..9
    #pragma unroll
    for (int c = 0; c < 10; c++) z[c] = (lane == c) ? 1.f : 0.f;

#define ZCASE(J)  { float a = z[(J)]; float bz = z[(J)-1];                 \
                    z[(J)] = c_*a - s_*bz;  z[(J)-1] = s_*a + c_*bz; }
    auto ZROT = [&](int jj, float c_, float s_){
        switch (jj){
            case 1: ZCASE(1) break;
            case 2: ZCASE(2) break;
            case 3: ZCASE(3) break;
            case 4: ZCASE(4) break;
            case 5: ZCASE(5) break;
            case 6: ZCASE(6) break;
            case 7: ZCASE(7) break;
            case 8: ZCASE(8) break;
            default: ZCASE(9) break;
        }
    };
#undef ZCASE

    // ---------------- ssteqr 'I' ----------------
    const float eps    = 0x1.0p-24f;
    const float eps2   = 0x1.0p-48f;
    const float safmin = 0x1.0p-126f;
    const int nmaxit = n * 30;
    int jtot = 0;
    int l1 = 1;

    while (true){
        if (l1 > n) break;
        if (l1 > 1){ if (lane == l1-1) ee_r = 0.f; }
        int m = n;
        if (l1 <= n-1){
            for (m = l1; m <= n-1; m++){
                float tst = fabsf(rl(ee_r, m));
                if (tst == 0.f) break;
                if (tst <= (sqrtf(fabsf(rl(dd_r, m))) * sqrtf(fabsf(rl(dd_r, m+1)))) * eps){
                    if (lane == m) ee_r = 0.f;
                    break;
                }
            }
        }
        int l = l1;
        int lsv = l;
        int lend = m;
        int lendsv = lend;
        l1 = m + 1;
        if (lend == l) continue;

        float anorm = 0.f;
        for (int k = l; k <= lend; k++)   anorm = fmaxf(anorm, fabsf(rl(dd_r, k)));
        for (int k = l; k <= lend-1; k++) anorm = fmaxf(anorm, fabsf(rl(ee_r, k)));
        if (anorm == 0.f) continue;

        if (fabsf(rl(dd_r, lend)) < fabsf(rl(dd_r, l))){
            lend = lsv;
            l = lendsv;
        }

        if (lend > l){
            // -------- QL --------
            while (true){
                int mq = lend;
                if (l != lend){
                    for (int t2 = l; t2 <= lend-1; t2++){
                        float ev = fabsf(rl(ee_r, t2));
                        if (ev*ev <= (eps2*fabsf(rl(dd_r, t2)))*fabsf(rl(dd_r, t2+1)) + safmin){
                            mq = t2; break;
                        }
                    }
                }
                if (mq < lend){ if (lane == mq) ee_r = 0.f; }
                float p = rl(dd_r, l);
                if (mq == l){
                    l = l + 1;
                    if (l <= lend) continue;
                    break;
                }
                if (mq == l+1){
                    float rt1, rt2, cc, ss;
                    slaev2(rl(dd_r, l), rl(ee_r, l), rl(dd_r, l+1), &rt1, &rt2, &cc, &ss);
                    ZROT(l, cc, ss);
                    if (lane == l)   dd_r = rt1;
                    if (lane == l+1) dd_r = rt2;
                    if (lane == l)   ee_r = 0.f;
                    l += 2;
                    if (l <= lend) continue;
                    break;
                }
                if (jtot == nmaxit) break;
                jtot++;
                float g = fdivf(rl(dd_r, l+1) - p, 2.f * rl(ee_r, l));
                float r0 = slapy2(g, 1.f);
                g = rl(dd_r, mq) - p + fdivf(rl(ee_r, l), g + f_sign(r0, g));
                float ss = 1.f, cc = 1.f;
                p = 0.f;
                for (int i2 = mq-1; i2 >= l; i2--){
                    float e2 = rl(ee_r, i2);
                    float ff = ss * e2;
                    float bb = cc * e2;
                    float rr;
                    slartg(g, ff, &cc, &ss, &rr);
                    if (i2 != mq-1){ if (lane == i2+1) ee_r = rr; }
                    g = rl(dd_r, i2+1) - p;
                    rr = (rl(dd_r, i2) - g)*ss + 2.f*cc*bb;
                    p = ss*rr;
                    if (lane == i2+1) dd_r = g + p;
                    g = cc*rr - bb;
                    if (lane == i2){ wkc_r = cc; wks_r = -ss; }
                }
                for (int jj = mq-1; jj >= l; jj--){
                    float ct = rl(wkc_r, jj), st = rl(wks_r, jj);
                    if (ct != 1.f || st != 0.f) ZROT(jj, ct, st);
                }
                if (lane == l) dd_r = dd_r - p;
                if (lane == l) ee_r = g;
            }
        } else {
            // -------- QR --------
            while (true){
                int mq = lend;
                if (l != lend){
                    for (int t2 = l; t2 >= lend+1; t2--){
                        float ev = fabsf(rl(ee_r, t2-1));
                        if (ev*ev <= (eps2*fabsf(rl(dd_r, t2)))*fabsf(rl(dd_r, t2-1)) + safmin){
                            mq = t2; break;
                        }
                    }
                }
                if (mq > lend){ if (lane == mq-1) ee_r = 0.f; }
                float p = rl(dd_r, l);
                if (mq == l){
                    l = l - 1;
                    if (l >= lend) continue;
                    break;
                }
                if (mq == l-1){
                    float rt1, rt2, cc, ss;
                    slaev2(rl(dd_r, l-1), rl(ee_r, l-1), rl(dd_r, l), &rt1, &rt2, &cc, &ss);
                    ZROT(l-1, cc, ss);
                    if (lane == l-1) dd_r = rt1;
                    if (lane == l)   dd_r = rt2;
                    if (lane == l-1) ee_r = 0.f;
                    l -= 2;
                    if (l >= lend) continue;
                    break;
                }
                if (jtot == nmaxit) break;
                jtot++;
                float g = fdivf(rl(dd_r, l-1) - p, 2.f * rl(ee_r, l-1));
                float r0 = slapy2(g, 1.f);
                g = rl(dd_r, mq) - p + fdivf(rl(ee_r, l-1), g + f_sign(r0, g));
                float ss = 1.f, cc = 1.f;
                p = 0.f;
                for (int i2 = mq; i2 <= l-1; i2++){
                    float e2 = rl(ee_r, i2);
                    float ff = ss * e2;
                    float bb = cc * e2;
                    float rr;
                    slartg(g, ff, &cc, &ss, &rr);
                    if (i2 != mq){ if (lane == i2-1) ee_r = rr; }
                    g = rl(dd_r, i2) - p;
                    rr = (rl(dd_r, i2+1) - g)*ss + 2.f*cc*bb;
                    p = ss*rr;
                    if (lane == i2) dd_r = g + p;
                    g = cc*rr - bb;
                    if (lane == i2){ wkc_r = cc; wks_r = ss; }
                }
                for (int jj = mq; jj <= l-1; jj++){
                    float ct = rl(wkc_r, jj), st = rl(wks_r, jj);
                    if (ct != 1.f || st != 0.f) ZROT(jj, ct, st);
                }
                if (lane == l)   dd_r = dd_r - p;
                if (lane == l-1) ee_r = g;
            }
        }
        if (jtot < nmaxit) continue;
        break;
    }

    // ---------------- argmax (ascending sort's last == max) ----------------
    int kmax = 1;
    float pmax = rl(dd_r, 1);
    for (int j = 2; j <= n; j++){
        float dj = rl(dd_r, j);
        if (dj > pmax){ pmax = dj; kmax = j; }
    }

    // extract column kmax (row-per-lane): lane L holds row L+1
    float vc;
    switch (kmax){
        case 1:  vc = z[0]; break;
        case 2:  vc = z[1]; break;
        case 3:  vc = z[2]; break;
        case 4:  vc = z[3]; break;
        case 5:  vc = z[4]; break;
        case 6:  vc = z[5]; break;
        case 7:  vc = z[6]; break;
        case 8:  vc = z[7]; break;
        case 9:  vc = z[8]; break;
        default: vc = z[9]; break;
    }

    // ---------------- sormtr 'L','L','N' on the single column ------------
    // row r lives on lane r-1.
    for (int i = n-1; i >= 1; i--){
        float taui = tt[i];
        if (taui != 0.f){
            float s1 = rl(vc, i);                       // row i+1
            for (int r2 = i+2; r2 <= n; r2++) s1 = s1 + A_(r2, i) * rl(vc, r2-1);
            s1 = taui * s1;
            if (lane == i) vc = vc - s1;                // row i+1
            if (lane >= i+1 && lane <= n-1)             // rows i+2..n
                vc = vc - A_(lane+1, i) * s1;
        }
    }
    if (lane < n) vout[lane] = vc;
}

// ======================= Kernel 2: D, eigh, outputs =======================
__global__ __launch_bounds__(64) void k2_eig(
        const float* __restrict__ partial, const float* __restrict__ tmpl,
        float* __restrict__ out, int cblk)
{
    __shared__ float SS[66];
    __shared__ float Aa[100];
    __shared__ float dd[12], ee[12], tt[12], px[12], vout[12];
    const int lane = threadIdx.x;
    const int b = blockIdx.x;

    for (int i = lane; i < 65; i += 64){
        float s = 0.f;
        for (int p = 0; p < cblk; p++)
            s += partial[((size_t)b*cblk + p)*65 + i];
        SS[i] = s;
    }
    __syncthreads();

    // D[t][s] = S2 - S1 S1^T / C (exactly symmetric), col-major in Aa
    for (int idx = lane; idx < 100; idx += 64){
        int t = idx % 10, s2 = idx / 10;
        int lo = t < s2 ? t : s2, hi = t < s2 ? s2 : t;
        int pk = 10*lo - (lo*(lo-1))/2 + (hi - lo);
        Aa[s2*10 + t] = SS[10 + pk] - SS[t]*SS[s2]*(1.0f/2048.0f);
    }
    __syncthreads();

    eig10_wave(lane, Aa, dd, ee, tt, px, vout);
    __syncthreads();

    if (lane < NTMP)
        out[(size_t)NB*NHW + (size_t)b*NTMP + lane] = vout[lane];

    for (int i = lane; i < NHW; i += 64){
        float m2 = 0.f;
        #pragma unroll
        for (int t = 0; t < NTMP; t++) m2 += vout[t] * tmpl[t*NHW + i];
        out[(size_t)b*NHW + i] = m2;
    }
}

// ============================== launcher ==================================
extern "C" void kernel_launch(void* const* d_in, const int* in_sizes, int n_in,
                              void* d_out, int out_size, void* d_ws, size_t ws_size,
                              hipStream_t stream)
{
    const float* x    = (const float*)d_in[0];
    const float* tmpl = (const float*)d_in[1];
    float* out = (float*)d_out;
    float* partial = (float*)d_ws;

    if (ws_size >= (size_t)NB*8*65*sizeof(float)){
        // 512 blocks x 512 threads: 2 blocks/CU, 16 waves/CU (4/SIMD)
        k1_partials<8><<<dim3(NB*8), dim3(512), 0, stream>>>(x, tmpl, partial);
        k2_eig<<<dim3(NB), dim3(64), 0, stream>>>(partial, tmpl, out, 8);
    } else if (ws_size >= (size_t)NB*4*65*sizeof(float)){
        k1_partials<4><<<dim3(NB*4), dim3(512), 0, stream>>>(x, tmpl, partial);
        k2_eig<<<dim3(NB), dim3(64), 0, stream>>>(partial, tmpl, out, 4);
    } else {
        k1_partials<2><<<dim3(NB*2), dim3(512), 0, stream>>>(x, tmpl, partial);
        k2_eig<<<dim3(NB), dim3(64), 0, stream>>>(partial, tmpl, out, 2);
    }
}